// Round 3
// baseline (3366.586 us; speedup 1.0000x reference)
//
#include <hip/hip_runtime.h>
#include <cstdio>

typedef unsigned short u16;
typedef float f32x4 __attribute__((ext_vector_type(4)));
typedef short s16x8 __attribute__((ext_vector_type(8)));

__device__ __forceinline__ u16 f2bf(float x) {
    unsigned u = __float_as_uint(x);
    u += 0x7fffu + ((u >> 16) & 1u);
    return (u16)(u >> 16);
}
__device__ __forceinline__ unsigned pack2(float a, float b) {
    return (unsigned)f2bf(a) | ((unsigned)f2bf(b) << 16);
}
__device__ __forceinline__ void unpack2(unsigned u, float& lo, float& hi) {
    lo = __uint_as_float(u << 16);
    hi = __uint_as_float(u & 0xffff0000u);
}

// load 8 logical elements as 8 packed bf16 (16B). bf16 source: direct.
// fp32 source: two float4 loads + round-to-nearest-even pack.
__device__ __forceinline__ uint4 ld8(const u16* p) { return *(const uint4*)p; }
__device__ __forceinline__ uint4 ld8(const float* p) {
    float4 a = ((const float4*)p)[0];
    float4 b = ((const float4*)p)[1];
    uint4 r;
    r.x = pack2(a.x, a.y);
    r.y = pack2(a.z, a.w);
    r.z = pack2(b.x, b.y);
    r.w = pack2(b.z, b.w);
    return r;
}

// ---------------- GEMM: C[M,N] = A[M,K] @ B[N,K]^T + bias ----------------
// A row-major (lda=K) dtype TA (float or u16/bf16); B row-major (ldb=K) dtype TB.
// bias fp32 len N. Tile 128x128, BK=32, 256 threads = 4 waves (2x2), each wave
// 64x64 via 4x4 mfma_f32_16x16x32_bf16. M=grid.y*128, N=grid.x*128; K%32==0.
template <typename TA, typename TB, bool OUT_BF16>
__global__ __launch_bounds__(256) void gemm_bt(const TA* __restrict__ A,
                                               const TB* __restrict__ B,
                                               const float* __restrict__ bias,
                                               void* __restrict__ Cout,
                                               int K, int ldc) {
    __shared__ __align__(16) u16 As[128 * 32];
    __shared__ __align__(16) u16 Bs[128 * 32];

    const int tid = threadIdx.x;
    const int lane = tid & 63;
    const int wave = tid >> 6;
    const int wm = wave >> 1;  // 0..1
    const int wn = wave & 1;   // 0..1
    const size_t bm = (size_t)blockIdx.y * 128;
    const size_t bn = (size_t)blockIdx.x * 128;

    f32x4 acc[4][4];
#pragma unroll
    for (int i = 0; i < 4; ++i)
#pragma unroll
        for (int j = 0; j < 4; ++j) acc[i][j] = (f32x4)0.f;

    // staging: 256 threads x 8 elems = 64 rows of 32 per round; 2 rounds each
    const int srow = tid >> 2;        // 0..63
    const int scol = (tid & 3) << 3;  // 0,8,16,24 (elements)
    const TA* Ag = A + (bm + (size_t)srow) * K + scol;
    const TB* Bg = B + (bn + (size_t)srow) * K + scol;
    const size_t rstep = (size_t)64 * K;

    // preload k-tile 0 into registers (bf16-packed)
    uint4 a0 = ld8(Ag);
    uint4 a1 = ld8(Ag + rstep);
    uint4 b0 = ld8(Bg);
    uint4 b1 = ld8(Bg + rstep);

    const int lrow = lane & 15;       // fragment row within 16
    const int lk = (lane >> 4) << 3;  // k-offset: quad*8

    const int niter = K >> 5;
    for (int t = 0; t < niter; ++t) {
        __syncthreads();  // previous iteration's LDS reads done
        *(uint4*)&As[srow * 32 + scol] = a0;
        *(uint4*)&As[(64 + srow) * 32 + scol] = a1;
        *(uint4*)&Bs[srow * 32 + scol] = b0;
        *(uint4*)&Bs[(64 + srow) * 32 + scol] = b1;
        __syncthreads();
        if (t + 1 < niter) {  // prefetch next k-tile while MFMAs run
            const int k0 = (t + 1) << 5;
            a0 = ld8(Ag + k0);
            a1 = ld8(Ag + rstep + k0);
            b0 = ld8(Bg + k0);
            b1 = ld8(Bg + rstep + k0);
        }
        s16x8 af[4], bfr[4];
#pragma unroll
        for (int i = 0; i < 4; ++i)
            af[i] = *(const s16x8*)&As[(wm * 64 + i * 16 + lrow) * 32 + lk];
#pragma unroll
        for (int j = 0; j < 4; ++j)
            bfr[j] = *(const s16x8*)&Bs[(wn * 64 + j * 16 + lrow) * 32 + lk];
#pragma unroll
        for (int i = 0; i < 4; ++i)
#pragma unroll
            for (int j = 0; j < 4; ++j)
                acc[i][j] = __builtin_amdgcn_mfma_f32_16x16x32_bf16(
                    af[i], bfr[j], acc[i][j], 0, 0, 0);
    }

    // epilogue: C/D layout col=lane&15, row=(lane>>4)*4+reg  [verified m89/m91]
    const size_t crow0 = bm + wm * 64 + ((lane >> 4) << 2);
    const int ccol0 = (int)bn + wn * 64 + (lane & 15);
#pragma unroll
    for (int i = 0; i < 4; ++i) {
#pragma unroll
        for (int j = 0; j < 4; ++j) {
            const int col = ccol0 + j * 16;
            const float bv = bias[col];
            const size_t base = (crow0 + (size_t)i * 16) * (size_t)ldc + col;
#pragma unroll
            for (int r = 0; r < 4; ++r) {
                const float v = acc[i][j][r] + bv;
                if (OUT_BF16)
                    ((u16*)Cout)[base + (size_t)r * ldc] = f2bf(v);
                else
                    ((float*)Cout)[base + (size_t)r * ldc] = v;
            }
        }
    }
}

// ---------------- tiny attention: S=2, one thread per (sample,head) --------
// qkv rows (token-major): row = 2*b+s, 6144 wide = [q|k|v] per token.
// grid*256 threads = CH*16; b in [0,CH).
__device__ __forceinline__ void dot8(uint4 a, uint4 b, float& acc) {
    const unsigned* pa = (const unsigned*)&a;
    const unsigned* pb = (const unsigned*)&b;
#pragma unroll
    for (int i = 0; i < 4; ++i) {
        float alo, ahi, blo, bhi;
        unpack2(pa[i], alo, ahi);
        unpack2(pb[i], blo, bhi);
        acc += alo * blo + ahi * bhi;
    }
}

__global__ __launch_bounds__(256) void attn2(const u16* __restrict__ qkv,
                                             u16* __restrict__ ctx) {
    const int gid = blockIdx.x * 256 + threadIdx.x;
    const int b = gid >> 4;
    const int h = gid & 15;
    const u16* base = qkv + (size_t)(2 * b) * 6144 + h * 128;
    // rows: q0=base, q1=+6144; k0=+2048, k1=+8192; v0=+4096, v1=+10240
    float s00 = 0.f, s01 = 0.f, s10 = 0.f, s11 = 0.f;
#pragma unroll 4
    for (int c = 0; c < 128; c += 8) {
        uint4 q0 = *(const uint4*)(base + c);
        uint4 q1 = *(const uint4*)(base + 6144 + c);
        uint4 k0 = *(const uint4*)(base + 2048 + c);
        uint4 k1 = *(const uint4*)(base + 8192 + c);
        dot8(q0, k0, s00);
        dot8(q0, k1, s01);
        dot8(q1, k0, s10);
        dot8(q1, k1, s11);
    }
    const float scale = 0.0883883476483184f;  // 1/sqrt(128)
    s00 *= scale; s01 *= scale; s10 *= scale; s11 *= scale;
    const float m0 = fmaxf(s00, s01), m1 = fmaxf(s10, s11);
    const float e00 = __expf(s00 - m0), e01 = __expf(s01 - m0);
    const float e10 = __expf(s10 - m1), e11 = __expf(s11 - m1);
    const float r0 = 1.f / (e00 + e01), r1 = 1.f / (e10 + e11);
    const float p00 = e00 * r0, p01 = e01 * r0;
    const float p10 = e10 * r1, p11 = e11 * r1;

    u16* o = ctx + (size_t)(2 * b) * 2048 + h * 128;
#pragma unroll 4
    for (int c = 0; c < 128; c += 8) {
        uint4 v0 = *(const uint4*)(base + 4096 + c);
        uint4 v1 = *(const uint4*)(base + 10240 + c);
        const unsigned* p0w = (const unsigned*)&v0;
        const unsigned* p1w = (const unsigned*)&v1;
        uint4 r0v, r1v;
        unsigned* q0w = (unsigned*)&r0v;
        unsigned* q1w = (unsigned*)&r1v;
#pragma unroll
        for (int i = 0; i < 4; ++i) {
            float v0lo, v0hi, v1lo, v1hi;
            unpack2(p0w[i], v0lo, v0hi);
            unpack2(p1w[i], v1lo, v1hi);
            q0w[i] = pack2(p00 * v0lo + p01 * v1lo, p00 * v0hi + p01 * v1hi);
            q1w[i] = pack2(p10 * v0lo + p11 * v1lo, p10 * v0hi + p11 * v1hi);
        }
        *(uint4*)(o + c) = r0v;
        *(uint4*)(o + 2048 + c) = r1v;
    }
}

// ---------------- LayerNorm over C=2048 (bf16 in/out), one block/row -------
__global__ __launch_bounds__(256) void ln_k(const u16* __restrict__ x,
                                            const float* __restrict__ w,
                                            const float* __restrict__ bb,
                                            u16* __restrict__ y) {
    __shared__ float red[8];
    const int row = blockIdx.x;
    const int tid = threadIdx.x;
    const uint4 v = ((const uint4*)(x + (size_t)row * 2048))[tid];  // 8 bf16
    const unsigned* pw = (const unsigned*)&v;
    float f[8];
#pragma unroll
    for (int i = 0; i < 4; ++i) unpack2(pw[i], f[2 * i], f[2 * i + 1]);
    float s = 0.f, q = 0.f;
#pragma unroll
    for (int i = 0; i < 8; ++i) {
        s += f[i];
        q += f[i] * f[i];
    }
#pragma unroll
    for (int off = 32; off > 0; off >>= 1) {
        s += __shfl_down(s, off);
        q += __shfl_down(q, off);
    }
    if ((tid & 63) == 0) {
        red[tid >> 6] = s;
        red[4 + (tid >> 6)] = q;
    }
    __syncthreads();
    s = red[0] + red[1] + red[2] + red[3];
    q = red[4] + red[5] + red[6] + red[7];
    const float mu = s * (1.f / 2048.f);
    const float var = q * (1.f / 2048.f) - mu * mu;
    const float rstd = rsqrtf(var + 1e-5f);
    const float4 w0 = ((const float4*)w)[2 * tid];
    const float4 w1 = ((const float4*)w)[2 * tid + 1];
    const float4 b0 = ((const float4*)bb)[2 * tid];
    const float4 b1 = ((const float4*)bb)[2 * tid + 1];
    const float wv[8] = {w0.x, w0.y, w0.z, w0.w, w1.x, w1.y, w1.z, w1.w};
    const float bv[8] = {b0.x, b0.y, b0.z, b0.w, b1.x, b1.y, b1.z, b1.w};
    uint4 o;
    unsigned* po = (unsigned*)&o;
#pragma unroll
    for (int i = 0; i < 4; ++i) {
        float lo = (f[2 * i] - mu) * rstd * wv[2 * i] + bv[2 * i];
        float hi = (f[2 * i + 1] - mu) * rstd * wv[2 * i + 1] + bv[2 * i + 1];
        po[i] = pack2(lo, hi);
    }
    ((uint4*)(y + (size_t)row * 2048))[tid] = o;
}

// ---------------- fused = mean_s(ln + cross) -> bf16 ----------------
__global__ __launch_bounds__(256) void mean_res(const u16* __restrict__ ln,
                                                const u16* __restrict__ co,
                                                u16* __restrict__ fused) {
    const int gid = blockIdx.x * 256 + threadIdx.x;  // CH*256
    const int b = gid >> 8;
    const int c8 = gid & 255;
    const uint4 l0 = ((const uint4*)ln)[(size_t)(2 * b) * 256 + c8];
    const uint4 l1 = ((const uint4*)ln)[(size_t)(2 * b + 1) * 256 + c8];
    const uint4 c0 = ((const uint4*)co)[(size_t)(2 * b) * 256 + c8];
    const uint4 c1 = ((const uint4*)co)[(size_t)(2 * b + 1) * 256 + c8];
    const unsigned* pl0 = (const unsigned*)&l0;
    const unsigned* pl1 = (const unsigned*)&l1;
    const unsigned* pc0 = (const unsigned*)&c0;
    const unsigned* pc1 = (const unsigned*)&c1;
    uint4 o;
    unsigned* po = (unsigned*)&o;
#pragma unroll
    for (int i = 0; i < 4; ++i) {
        float a_lo, a_hi, b_lo, b_hi, c_lo, c_hi, d_lo, d_hi;
        unpack2(pl0[i], a_lo, a_hi);
        unpack2(pl1[i], b_lo, b_hi);
        unpack2(pc0[i], c_lo, c_hi);
        unpack2(pc1[i], d_lo, d_hi);
        po[i] = pack2(0.5f * (a_lo + c_lo + b_lo + d_lo),
                      0.5f * (a_hi + c_hi + b_hi + d_hi));
    }
    ((uint4*)fused)[gid] = o;
}

extern "C" void kernel_launch(void* const* d_in, const int* in_sizes, int n_in,
                              void* d_out, int out_size, void* d_ws, size_t ws_size,
                              hipStream_t stream) {
    (void)in_sizes; (void)n_in; (void)out_size;
    const float* text   = (const float*)d_in[0];
    const float* graph  = (const float*)d_in[1];
    const float* Wt     = (const float*)d_in[2];
    const float* bt     = (const float*)d_in[3];
    const float* Wg     = (const float*)d_in[4];
    const float* bg     = (const float*)d_in[5];
    const float* Wqkv_s = (const float*)d_in[6];
    const float* bqkv_s = (const float*)d_in[7];
    const float* Wo_s   = (const float*)d_in[8];
    const float* bo_s   = (const float*)d_in[9];
    const float* Wqkv_c = (const float*)d_in[10];
    const float* bqkv_c = (const float*)d_in[11];
    const float* Wo_c   = (const float*)d_in[12];
    const float* bo_c   = (const float*)d_in[13];
    const float* ln_w   = (const float*)d_in[14];
    const float* ln_b   = (const float*)d_in[15];
    const float* Wout   = (const float*)d_in[16];
    const float* bout   = (const float*)d_in[17];
    float* out = (float*)d_out;

    // ---- pick chunk size so scratch fits ws_size (deterministic per run) ----
    // per-chunk need: stacked 8192T + ctx 8192T + ln 8192T + qkv 24576T bytes,
    // T = 2*CH tokens; fused aliases ctx; ao/co alias qkv. total = 98304*CH.
    size_t CH = 8192;
    while (CH > 128 && 98304ull * CH > ws_size) CH >>= 1;
    fprintf(stderr, "[kernel_launch] ws_size=%zu need=%zu CH=%zu\n",
            ws_size, 98304ull * CH, CH);
    if (98304ull * CH > ws_size || d_ws == nullptr) return;  // can't fit: bail cleanly

    const size_t T = 2 * CH;  // token rows per chunk
    char* ws = (char*)d_ws;
    u16* stacked_c = (u16*)(ws);               // [0, 8192T)
    u16* ctx_c     = (u16*)(ws + 8192 * T);    // [8192T, 16384T)
    u16* fused_c   = (u16*)(ws + 8192 * T);    // alias ctx (dead by mean_res)
    u16* ln_c      = (u16*)(ws + 16384 * T);   // [16384T, 24576T)
    u16* qkv_c     = (u16*)(ws + 24576 * T);   // [24576T, 49152T)
    u16* ao_c      = qkv_c;                    // alias (qkv dead after attn)
    u16* co_c      = qkv_c;                    // alias

    const dim3 blk(256);
    const unsigned gy = (unsigned)(CH / 128);      // sample-row tiles
    const unsigned gyT = (unsigned)(T / 128);      // token-row tiles

    for (size_t c0 = 0; c0 < 8192; c0 += CH) {
        // S2: projections -> interleaved stacked (token row 2m=text, 2m+1=graph)
        gemm_bt<float, float, true><<<dim3(16, gy), blk, 0, stream>>>(
            text + c0 * 2048, Wt, bt, stacked_c, 2048, 4096);
        gemm_bt<float, float, true><<<dim3(16, gy), blk, 0, stream>>>(
            graph + c0 * 1024, Wg, bg, stacked_c + 2048, 1024, 4096);
        // S3: self QKV + attention
        gemm_bt<u16, float, true><<<dim3(48, gyT), blk, 0, stream>>>(
            stacked_c, Wqkv_s, bqkv_s, qkv_c, 2048, 6144);
        attn2<<<(unsigned)(CH / 16), blk, 0, stream>>>(qkv_c, ctx_c);
        // S4: self Wo -> bf16 (ao aliases qkv region)
        gemm_bt<u16, float, true><<<dim3(16, gyT), blk, 0, stream>>>(
            ctx_c, Wo_s, bo_s, ao_c, 2048, 2048);
        // S5: LayerNorm
        ln_k<<<(unsigned)T, blk, 0, stream>>>(ao_c, ln_w, ln_b, ln_c);
        // S6: cross QKV (Q from ln, K/V from stacked) + attention
        gemm_bt<u16, float, true><<<dim3(16, gyT), blk, 0, stream>>>(
            ln_c, Wqkv_c, bqkv_c, qkv_c, 2048, 6144);
        gemm_bt<u16, float, true><<<dim3(32, gyT), blk, 0, stream>>>(
            stacked_c, Wqkv_c + 2048ull * 2048, bqkv_c + 2048,
            qkv_c + 2048, 2048, 6144);
        attn2<<<(unsigned)(CH / 16), blk, 0, stream>>>(qkv_c, ctx_c);
        // S7: cross Wo -> bf16 (co aliases qkv region)
        gemm_bt<u16, float, true><<<dim3(16, gyT), blk, 0, stream>>>(
            ctx_c, Wo_c, bo_c, co_c, 2048, 2048);
        // S8: fused = mean_s(ln + cross) (fused aliases ctx region)
        mean_res<<<(unsigned)CH, blk, 0, stream>>>(ln_c, co_c, fused_c);
        // S9: final projection -> d_out fp32
        gemm_bt<u16, float, false><<<dim3(8, gy), blk, 0, stream>>>(
            fused_c, Wout, bout, out + c0 * 1024, 2048, 1024);
    }
}

// Round 4
// 2395.294 us; speedup vs baseline: 1.4055x; 1.4055x over previous
//
#include <hip/hip_runtime.h>
#include <cstdio>

typedef unsigned short u16;
typedef float f32x4 __attribute__((ext_vector_type(4)));
typedef short s16x8 __attribute__((ext_vector_type(8)));

__device__ __forceinline__ u16 f2bf(float x) {
    unsigned u = __float_as_uint(x);
    u += 0x7fffu + ((u >> 16) & 1u);
    return (u16)(u >> 16);
}
__device__ __forceinline__ unsigned pack2(float a, float b) {
    return (unsigned)f2bf(a) | ((unsigned)f2bf(b) << 16);
}
__device__ __forceinline__ void unpack2(unsigned u, float& lo, float& hi) {
    lo = __uint_as_float(u << 16);
    hi = __uint_as_float(u & 0xffff0000u);
}

// async global->LDS, 16B per lane; LDS dest must be wave-uniform base + lane*16
__device__ __forceinline__ void gl2lds16(const u16* g, u16* l) {
    __builtin_amdgcn_global_load_lds(
        (const __attribute__((address_space(1))) void*)g,
        (__attribute__((address_space(3))) void*)l, 16, 0, 0);
}

// load 8 logical elements as 8 packed bf16 (16B)
__device__ __forceinline__ uint4 ld8(const u16* p) { return *(const uint4*)p; }
__device__ __forceinline__ uint4 ld8(const float* p) {
    float4 a = ((const float4*)p)[0];
    float4 b = ((const float4*)p)[1];
    uint4 r;
    r.x = pack2(a.x, a.y);
    r.y = pack2(a.z, a.w);
    r.z = pack2(b.x, b.y);
    r.w = pack2(b.z, b.w);
    return r;
}

// ---------------- cast fp32 -> bf16 (4 elems/thread) ----------------
__global__ __launch_bounds__(256) void cast_f32_bf16(const float* __restrict__ x,
                                                     u16* __restrict__ y, int n4) {
    int i = blockIdx.x * 256 + threadIdx.x;
    if (i >= n4) return;
    float4 v = ((const float4*)x)[i];
    uint2 r;
    r.x = pack2(v.x, v.y);
    r.y = pack2(v.z, v.w);
    ((uint2*)y)[i] = r;
}

// ---------------- register-staged GEMM (fp32 A, bf16 B) — projections only --
// C[M,N] = A[M,K] @ B[N,K]^T + bias. lda=ldb=K. Tile 128x128, BK=32.
template <typename TA, typename TB, bool OUT_BF16>
__global__ __launch_bounds__(256) void gemm_bt(const TA* __restrict__ A,
                                               const TB* __restrict__ B,
                                               const float* __restrict__ bias,
                                               void* __restrict__ Cout,
                                               int K, int ldc) {
    __shared__ __align__(16) u16 As[128 * 32];
    __shared__ __align__(16) u16 Bs[128 * 32];

    const int tid = threadIdx.x;
    const int lane = tid & 63;
    const int wave = tid >> 6;
    const int wm = wave >> 1;
    const int wn = wave & 1;
    const size_t bm = (size_t)blockIdx.y * 128;
    const size_t bn = (size_t)blockIdx.x * 128;

    f32x4 acc[4][4];
#pragma unroll
    for (int i = 0; i < 4; ++i)
#pragma unroll
        for (int j = 0; j < 4; ++j) acc[i][j] = (f32x4)0.f;

    const int srow = tid >> 2;
    const int scol = (tid & 3) << 3;
    const TA* Ag = A + (bm + (size_t)srow) * K + scol;
    const TB* Bg = B + (bn + (size_t)srow) * K + scol;
    const size_t rstep = (size_t)64 * K;

    uint4 a0 = ld8(Ag);
    uint4 a1 = ld8(Ag + rstep);
    uint4 b0 = ld8(Bg);
    uint4 b1 = ld8(Bg + rstep);

    const int lrow = lane & 15;
    const int lk = (lane >> 4) << 3;

    const int niter = K >> 5;
    for (int t = 0; t < niter; ++t) {
        __syncthreads();
        *(uint4*)&As[srow * 32 + scol] = a0;
        *(uint4*)&As[(64 + srow) * 32 + scol] = a1;
        *(uint4*)&Bs[srow * 32 + scol] = b0;
        *(uint4*)&Bs[(64 + srow) * 32 + scol] = b1;
        __syncthreads();
        if (t + 1 < niter) {
            const int k0 = (t + 1) << 5;
            a0 = ld8(Ag + k0);
            a1 = ld8(Ag + rstep + k0);
            b0 = ld8(Bg + k0);
            b1 = ld8(Bg + rstep + k0);
        }
        s16x8 af[4], bfr[4];
#pragma unroll
        for (int i = 0; i < 4; ++i)
            af[i] = *(const s16x8*)&As[(wm * 64 + i * 16 + lrow) * 32 + lk];
#pragma unroll
        for (int j = 0; j < 4; ++j)
            bfr[j] = *(const s16x8*)&Bs[(wn * 64 + j * 16 + lrow) * 32 + lk];
#pragma unroll
        for (int i = 0; i < 4; ++i)
#pragma unroll
            for (int j = 0; j < 4; ++j)
                acc[i][j] = __builtin_amdgcn_mfma_f32_16x16x32_bf16(
                    af[i], bfr[j], acc[i][j], 0, 0, 0);
    }

    // C/D layout: col=lane&15, row=(lane>>4)*4+reg  [verified m89/m91]
    const size_t crow0 = bm + wm * 64 + ((lane >> 4) << 2);
    const int ccol0 = (int)bn + wn * 64 + (lane & 15);
#pragma unroll
    for (int i = 0; i < 4; ++i) {
#pragma unroll
        for (int j = 0; j < 4; ++j) {
            const int col = ccol0 + j * 16;
            const float bv = bias[col];
            const size_t base = (crow0 + (size_t)i * 16) * (size_t)ldc + col;
#pragma unroll
            for (int r = 0; r < 4; ++r) {
                const float v = acc[i][j][r] + bv;
                if (OUT_BF16)
                    ((u16*)Cout)[base + (size_t)r * ldc] = f2bf(v);
                else
                    ((float*)Cout)[base + (size_t)r * ldc] = v;
            }
        }
    }
}

// ---------------- async-staged GEMM (bf16 A w/ stride, bf16 B dense) --------
// C[M,N] = A[M,K] @ B[N,K]^T + bias; A row stride lda, B row stride K.
// m97 structure: 2-barrier K-loop, global_load_lds width=16.
template <bool OUT_BF16>
__global__ __launch_bounds__(256) void gemm_async(const u16* __restrict__ A, int lda,
                                                  const u16* __restrict__ B,
                                                  const float* __restrict__ bias,
                                                  void* __restrict__ Cout,
                                                  int K, int ldc) {
    __shared__ __align__(16) u16 As[128 * 32];
    __shared__ __align__(16) u16 Bs[128 * 32];

    const int tid = threadIdx.x;
    const int lane = tid & 63;
    const int wave = tid >> 6;
    const int wm = wave >> 1;
    const int wn = wave & 1;
    const size_t bm = (size_t)blockIdx.y * 128;
    const size_t bn = (size_t)blockIdx.x * 128;

    f32x4 acc[4][4];
#pragma unroll
    for (int i = 0; i < 4; ++i)
#pragma unroll
        for (int j = 0; j < 4; ++j) acc[i][j] = (f32x4)0.f;

    const int srow = tid >> 2;        // 0..63
    const int scol = (tid & 3) << 3;  // 0,8,16,24
    const u16* Ag = A + (bm + (size_t)srow) * (size_t)lda + scol;
    const u16* Bg = B + (bn + (size_t)srow) * (size_t)K + scol;
    const size_t rA = (size_t)64 * lda;
    const size_t rB = (size_t)64 * K;
    // LDS byte dest = tid*16  ==  wave-uniform base (wave*1024) + lane*16  ✓
    u16* lA0 = &As[tid * 8];
    u16* lA1 = &As[2048 + tid * 8];
    u16* lB0 = &Bs[tid * 8];
    u16* lB1 = &Bs[2048 + tid * 8];

    const int lrow = lane & 15;
    const int lk = (lane >> 4) << 3;

    const int niter = K >> 5;
    for (int t = 0; t < niter; ++t) {
        __syncthreads();  // LDS consumers of previous tile done
        gl2lds16(Ag, lA0);
        gl2lds16(Ag + rA, lA1);
        gl2lds16(Bg, lB0);
        gl2lds16(Bg + rB, lB1);
        Ag += 32;
        Bg += 32;
        __syncthreads();  // compiler emits vmcnt(0) drain before barrier
        s16x8 af[4], bfr[4];
#pragma unroll
        for (int i = 0; i < 4; ++i)
            af[i] = *(const s16x8*)&As[(wm * 64 + i * 16 + lrow) * 32 + lk];
#pragma unroll
        for (int j = 0; j < 4; ++j)
            bfr[j] = *(const s16x8*)&Bs[(wn * 64 + j * 16 + lrow) * 32 + lk];
#pragma unroll
        for (int i = 0; i < 4; ++i)
#pragma unroll
            for (int j = 0; j < 4; ++j)
                acc[i][j] = __builtin_amdgcn_mfma_f32_16x16x32_bf16(
                    af[i], bfr[j], acc[i][j], 0, 0, 0);
    }

    const size_t crow0 = bm + wm * 64 + ((lane >> 4) << 2);
    const int ccol0 = (int)bn + wn * 64 + (lane & 15);
#pragma unroll
    for (int i = 0; i < 4; ++i) {
#pragma unroll
        for (int j = 0; j < 4; ++j) {
            const int col = ccol0 + j * 16;
            const float bv = bias[col];
            const size_t base = (crow0 + (size_t)i * 16) * (size_t)ldc + col;
#pragma unroll
            for (int r = 0; r < 4; ++r) {
                const float v = acc[i][j][r] + bv;
                if (OUT_BF16)
                    ((u16*)Cout)[base + (size_t)r * ldc] = f2bf(v);
                else
                    ((float*)Cout)[base + (size_t)r * ldc] = v;
            }
        }
    }
}

// ---------------- tiny attention S=2, IN-PLACE: ctx overwrites q-region -----
// qkv row = token (stride 6144): [q|k|v]. One thread per (sample,head).
__device__ __forceinline__ void dot8(uint4 a, uint4 b, float& acc) {
    const unsigned* pa = (const unsigned*)&a;
    const unsigned* pb = (const unsigned*)&b;
#pragma unroll
    for (int i = 0; i < 4; ++i) {
        float alo, ahi, blo, bhi;
        unpack2(pa[i], alo, ahi);
        unpack2(pb[i], blo, bhi);
        acc += alo * blo + ahi * bhi;
    }
}

__global__ __launch_bounds__(256) void attn2(u16* __restrict__ qkv) {
    const int gid = blockIdx.x * 256 + threadIdx.x;  // CH*16 threads
    const int b = gid >> 4;
    const int h = gid & 15;
    u16* base = qkv + (size_t)(2 * b) * 6144 + h * 128;
    float s00 = 0.f, s01 = 0.f, s10 = 0.f, s11 = 0.f;
#pragma unroll 4
    for (int c = 0; c < 128; c += 8) {
        uint4 q0 = *(const uint4*)(base + c);
        uint4 q1 = *(const uint4*)(base + 6144 + c);
        uint4 k0 = *(const uint4*)(base + 2048 + c);
        uint4 k1 = *(const uint4*)(base + 8192 + c);
        dot8(q0, k0, s00);
        dot8(q0, k1, s01);
        dot8(q1, k0, s10);
        dot8(q1, k1, s11);
    }
    const float scale = 0.0883883476483184f;  // 1/sqrt(128)
    s00 *= scale; s01 *= scale; s10 *= scale; s11 *= scale;
    const float m0 = fmaxf(s00, s01), m1 = fmaxf(s10, s11);
    const float e00 = __expf(s00 - m0), e01 = __expf(s01 - m0);
    const float e10 = __expf(s10 - m1), e11 = __expf(s11 - m1);
    const float r0 = 1.f / (e00 + e01), r1 = 1.f / (e10 + e11);
    const float p00 = e00 * r0, p01 = e01 * r0;
    const float p10 = e10 * r1, p11 = e11 * r1;

#pragma unroll 4
    for (int c = 0; c < 128; c += 8) {
        uint4 v0 = *(const uint4*)(base + 4096 + c);
        uint4 v1 = *(const uint4*)(base + 10240 + c);
        const unsigned* p0w = (const unsigned*)&v0;
        const unsigned* p1w = (const unsigned*)&v1;
        uint4 r0v, r1v;
        unsigned* q0w = (unsigned*)&r0v;
        unsigned* q1w = (unsigned*)&r1v;
#pragma unroll
        for (int i = 0; i < 4; ++i) {
            float v0lo, v0hi, v1lo, v1hi;
            unpack2(p0w[i], v0lo, v0hi);
            unpack2(p1w[i], v1lo, v1hi);
            q0w[i] = pack2(p00 * v0lo + p01 * v1lo, p00 * v0hi + p01 * v1hi);
            q1w[i] = pack2(p10 * v0lo + p11 * v1lo, p10 * v0hi + p11 * v1hi);
        }
        *(uint4*)(base + c) = r0v;           // ctx token0 -> q-region
        *(uint4*)(base + 6144 + c) = r1v;    // ctx token1 -> q-region
    }
}

// ---------------- LayerNorm C=2048 (bf16 in strided / out dense) ------------
__global__ __launch_bounds__(256) void ln_k(const u16* __restrict__ x, int ldx,
                                            const float* __restrict__ w,
                                            const float* __restrict__ bb,
                                            u16* __restrict__ y) {
    __shared__ float red[8];
    const int row = blockIdx.x;
    const int tid = threadIdx.x;
    const uint4 v = ((const uint4*)(x + (size_t)row * ldx))[tid];
    const unsigned* pw = (const unsigned*)&v;
    float f[8];
#pragma unroll
    for (int i = 0; i < 4; ++i) unpack2(pw[i], f[2 * i], f[2 * i + 1]);
    float s = 0.f, q = 0.f;
#pragma unroll
    for (int i = 0; i < 8; ++i) {
        s += f[i];
        q += f[i] * f[i];
    }
#pragma unroll
    for (int off = 32; off > 0; off >>= 1) {
        s += __shfl_down(s, off);
        q += __shfl_down(q, off);
    }
    if ((tid & 63) == 0) {
        red[tid >> 6] = s;
        red[4 + (tid >> 6)] = q;
    }
    __syncthreads();
    s = red[0] + red[1] + red[2] + red[3];
    q = red[4] + red[5] + red[6] + red[7];
    const float mu = s * (1.f / 2048.f);
    const float var = q * (1.f / 2048.f) - mu * mu;
    const float rstd = rsqrtf(var + 1e-5f);
    const float4 w0 = ((const float4*)w)[2 * tid];
    const float4 w1 = ((const float4*)w)[2 * tid + 1];
    const float4 b0 = ((const float4*)bb)[2 * tid];
    const float4 b1 = ((const float4*)bb)[2 * tid + 1];
    const float wv[8] = {w0.x, w0.y, w0.z, w0.w, w1.x, w1.y, w1.z, w1.w};
    const float bv[8] = {b0.x, b0.y, b0.z, b0.w, b1.x, b1.y, b1.z, b1.w};
    uint4 o;
    unsigned* po = (unsigned*)&o;
#pragma unroll
    for (int i = 0; i < 4; ++i) {
        float lo = (f[2 * i] - mu) * rstd * wv[2 * i] + bv[2 * i];
        float hi = (f[2 * i + 1] - mu) * rstd * wv[2 * i + 1] + bv[2 * i + 1];
        po[i] = pack2(lo, hi);
    }
    ((uint4*)(y + (size_t)row * 2048))[tid] = o;
}

// ------- fused = 0.5*(ln0+co0+ln1+co1); ln dense 2048, co stride 6144, ------
// ------- fused written at sample stride 12288 (q-region of token 2b) --------
__global__ __launch_bounds__(256) void mean_res(const u16* __restrict__ ln,
                                                const u16* __restrict__ co,
                                                u16* __restrict__ fused) {
    const int gid = blockIdx.x * 256 + threadIdx.x;  // CH*256
    const int b = gid >> 8;
    const int c8 = gid & 255;
    const uint4 l0 = ((const uint4*)(ln + (size_t)(2 * b) * 2048))[c8];
    const uint4 l1 = ((const uint4*)(ln + (size_t)(2 * b + 1) * 2048))[c8];
    const uint4 c0 = ((const uint4*)(co + (size_t)(2 * b) * 6144))[c8];
    const uint4 c1 = ((const uint4*)(co + (size_t)(2 * b + 1) * 6144))[c8];
    const unsigned* pl0 = (const unsigned*)&l0;
    const unsigned* pl1 = (const unsigned*)&l1;
    const unsigned* pc0 = (const unsigned*)&c0;
    const unsigned* pc1 = (const unsigned*)&c1;
    uint4 o;
    unsigned* po = (unsigned*)&o;
#pragma unroll
    for (int i = 0; i < 4; ++i) {
        float a_lo, a_hi, b_lo, b_hi, c_lo, c_hi, d_lo, d_hi;
        unpack2(pl0[i], a_lo, a_hi);
        unpack2(pl1[i], b_lo, b_hi);
        unpack2(pc0[i], c_lo, c_hi);
        unpack2(pc1[i], d_lo, d_hi);
        po[i] = pack2(0.5f * (a_lo + c_lo + b_lo + d_lo),
                      0.5f * (a_hi + c_hi + b_hi + d_hi));
    }
    ((uint4*)(fused + (size_t)b * 12288))[c8] = o;
}

extern "C" void kernel_launch(void* const* d_in, const int* in_sizes, int n_in,
                              void* d_out, int out_size, void* d_ws, size_t ws_size,
                              hipStream_t stream) {
    (void)in_sizes; (void)n_in; (void)out_size;
    const float* text   = (const float*)d_in[0];
    const float* graph  = (const float*)d_in[1];
    const float* Wt     = (const float*)d_in[2];
    const float* bt     = (const float*)d_in[3];
    const float* Wg     = (const float*)d_in[4];
    const float* bg     = (const float*)d_in[5];
    const float* Wqkv_s = (const float*)d_in[6];
    const float* bqkv_s = (const float*)d_in[7];
    const float* Wo_s   = (const float*)d_in[8];
    const float* bo_s   = (const float*)d_in[9];
    const float* Wqkv_c = (const float*)d_in[10];
    const float* bqkv_c = (const float*)d_in[11];
    const float* Wo_c   = (const float*)d_in[12];
    const float* bo_c   = (const float*)d_in[13];
    const float* ln_w   = (const float*)d_in[14];
    const float* ln_b   = (const float*)d_in[15];
    const float* Wout   = (const float*)d_in[16];
    const float* bout   = (const float*)d_in[17];
    float* out = (float*)d_out;

    // ---- weight area: 80 MiB of bf16 casts at base of ws ----
    char* ws = (char*)d_ws;
    u16* wQs  = (u16*)ws;                          // 12,582,912 elems
    u16* wQc  = wQs + 12582912ull;
    u16* wOs  = wQc + 12582912ull;                 // 4,194,304
    u16* wOc  = wOs + 4194304ull;
    u16* wWt  = wOc + 4194304ull;                  // 4,194,304
    u16* wWg  = wWt + 4194304ull;                  // 2,097,152
    u16* wOut = wWg + 2097152ull;                  // 2,097,152
    const size_t WB = 83886080ull;                 // 80 MiB weight area

    // ---- chunk size: per-sample scratch = stacked 8KB + ln 8KB + qkv 24KB ----
    size_t CH = 8192;
    while (CH > 128 && WB + 40960ull * CH > ws_size) CH >>= 1;
    fprintf(stderr, "[kernel_launch] ws_size=%zu need=%zu CH=%zu\n",
            ws_size, WB + 40960ull * CH, CH);
    if (WB + 40960ull * CH > ws_size || d_ws == nullptr) return;

    const size_t T = 2 * CH;
    char* ca = ws + WB;                            // chunk area
    u16* stacked_c = (u16*)ca;                     // T*2048 elems, dense
    u16* ln_c      = (u16*)(ca + 4096 * T);        // T*2048 elems, dense
    u16* qkv_c     = (u16*)(ca + 8192 * T);        // T*6144 elems, stride 6144

    // ---- one-time weight casts (stream-ordered before first GEMM) ----
    auto cast = [&](const float* x, u16* y, size_t n) {
        int n4 = (int)(n >> 2);
        cast_f32_bf16<<<(n4 + 255) / 256, 256, 0, stream>>>(x, y, n4);
    };
    cast(Wqkv_s, wQs, 12582912ull);
    cast(Wqkv_c, wQc, 12582912ull);
    cast(Wo_s, wOs, 4194304ull);
    cast(Wo_c, wOc, 4194304ull);
    cast(Wt, wWt, 4194304ull);
    cast(Wg, wWg, 2097152ull);
    cast(Wout, wOut, 2097152ull);

    const dim3 blk(256);
    const unsigned gy  = (unsigned)(CH / 128);
    const unsigned gyT = (unsigned)(T / 128);

    for (size_t c0 = 0; c0 < 8192; c0 += CH) {
        // S2: projections -> interleaved stacked (token 2m=text, 2m+1=graph)
        gemm_bt<float, u16, true><<<dim3(16, gy), blk, 0, stream>>>(
            text + c0 * 2048, wWt, bt, stacked_c, 2048, 4096);
        gemm_bt<float, u16, true><<<dim3(16, gy), blk, 0, stream>>>(
            graph + c0 * 1024, wWg, bg, stacked_c + 2048, 1024, 4096);
        // S3: self QKV -> qkv (ldc 6144), then in-place attention (ctx -> q-region)
        gemm_async<true><<<dim3(48, gyT), blk, 0, stream>>>(
            stacked_c, 2048, wQs, bqkv_s, qkv_c, 2048, 6144);
        attn2<<<(unsigned)(CH / 16), blk, 0, stream>>>(qkv_c);
        // S4: self Wo: A=ctx (q-region, lda 6144) -> ao (v-region, ldc 6144)
        gemm_async<true><<<dim3(16, gyT), blk, 0, stream>>>(
            qkv_c, 6144, wOs, bo_s, qkv_c + 4096, 2048, 6144);
        // S5: LayerNorm: ao (stride 6144) -> ln dense
        ln_k<<<(unsigned)T, blk, 0, stream>>>(qkv_c + 4096, 6144, ln_w, ln_b, ln_c);
        // S6: cross QKV: Q from ln -> q-region; K/V from stacked -> k,v regions
        gemm_async<true><<<dim3(16, gyT), blk, 0, stream>>>(
            ln_c, 2048, wQc, bqkv_c, qkv_c, 2048, 6144);
        gemm_async<true><<<dim3(32, gyT), blk, 0, stream>>>(
            stacked_c, 2048, wQc + 2048ull * 2048, bqkv_c + 2048,
            qkv_c + 2048, 2048, 6144);
        attn2<<<(unsigned)(CH / 16), blk, 0, stream>>>(qkv_c);
        // S7: cross Wo: A=ctx' (q-region) -> co (v-region)
        gemm_async<true><<<dim3(16, gyT), blk, 0, stream>>>(
            qkv_c, 6144, wOc, bo_c, qkv_c + 4096, 2048, 6144);
        // S8: fused = mean_s(ln + co) -> q-region rows 2b (sample stride 12288)
        mean_res<<<(unsigned)CH, blk, 0, stream>>>(ln_c, qkv_c + 4096, qkv_c);
        // S9: final projection: A=fused (lda 12288) -> d_out fp32
        gemm_async<false><<<dim3(8, gy), blk, 0, stream>>>(
            qkv_c, 12288, wOut, bout, out + c0 * 1024, 2048, 1024);
    }
}